// Round 1
// baseline (115.727 us; speedup 1.0000x reference)
//
#include <hip/hip_runtime.h>

#define NBLOCKS 1024
#define NTHREADS 256
#define FEPS 1e-7f

// Predicated write of (vx,vy) into slot idx of register arrays x,y.
// Fully unrolled -> pure v_cmp + v_cndmask, no scratch.
__device__ __forceinline__ void store_slot(float (&x)[8], float (&y)[8],
                                           bool pred, int idx, float vx, float vy) {
#pragma unroll
    for (int j = 0; j < 8; ++j) {
        bool w = pred && (j == idx);
        x[j] = w ? vx : x[j];
        y[j] = w ? vy : y[j];
    }
}

// One Sutherland-Hodgman half-plane clip, replicating the reference's exact
// semantics (MAXV=8 iteration count, valid=i<n masking, idx=min(m,7) clamp,
// pts[(i+1) % max(n,1)] with JAX OOB clamp-to-7, EPS denominator guard).
__device__ __forceinline__ int clip_halfplane(float (&bx)[8], float (&by)[8], int n,
                                              float Ax, float Ay, float ex, float ey) {
    float ox[8], oy[8];
#pragma unroll
    for (int j = 0; j < 8; ++j) { ox[j] = 0.0f; oy[j] = 0.0f; }
    int m = 0;
#pragma unroll
    for (int i = 0; i < 8; ++i) {
        bool valid = i < n;
        float cx = bx[i], cy = by[i];
        // nxt = pts[(i+1) % max(n,1)]; for valid lanes this is
        //   (i+1==n) ? pts[0] : pts[min(i+1,7)]   (JAX clamps OOB gather)
        int ip1 = (i < 7) ? (i + 1) : 7;           // static per unrolled i
        bool wrap = (i + 1 == n);
        float nx = wrap ? bx[0] : bx[ip1];
        float ny = wrap ? by[0] : by[ip1];

        float dc = ex * (cy - Ay) - ey * (cx - Ax);
        float dn = ex * (ny - Ay) - ey * (nx - Ax);
        float denom = dc - dn;
        float d = (fabsf(denom) < FEPS) ? 1.0f : denom;
        float t = dc / d;
        float ipx = cx + t * (nx - cx);
        float ipy = cy + t * (ny - cy);

        bool sc = (dc >= 0.0f);
        bool sn = (dn >= 0.0f);

        bool add_cur = valid && sc;
        store_slot(ox, oy, add_cur, (m < 7) ? m : 7, cx, cy);
        m += add_cur ? 1 : 0;

        bool add_ip = valid && (sc != sn);
        store_slot(ox, oy, add_ip, (m < 7) ? m : 7, ipx, ipy);
        m += add_ip ? 1 : 0;
    }
#pragma unroll
    for (int j = 0; j < 8; ++j) { bx[j] = ox[j]; by[j] = oy[j]; }
    return m;
}

__device__ __forceinline__ float diou_quad(float4 pa, float4 pb, float4 ta, float4 tb) {
    float px[4] = {pa.x, pa.z, pb.x, pb.z};
    float py[4] = {pa.y, pa.w, pb.y, pb.w};
    float tx[4] = {ta.x, ta.z, tb.x, tb.z};
    float ty[4] = {ta.y, ta.w, tb.y, tb.w};

    float sa_p = 0.5f * ((px[0] * py[1] - py[0] * px[1]) +
                         (px[1] * py[2] - py[1] * px[2]) +
                         (px[2] * py[3] - py[2] * px[3]) +
                         (px[3] * py[0] - py[3] * px[0]));
    float sa_t = 0.5f * ((tx[0] * ty[1] - ty[0] * tx[1]) +
                         (tx[1] * ty[2] - ty[1] * tx[2]) +
                         (tx[2] * ty[3] - ty[2] * tx[3]) +
                         (tx[3] * ty[0] - ty[3] * tx[0]));

    // orient CCW (reverse if signed area negative)
    if (sa_p < 0.0f) {
        float t0;
        t0 = px[0]; px[0] = px[3]; px[3] = t0;
        t0 = px[1]; px[1] = px[2]; px[2] = t0;
        t0 = py[0]; py[0] = py[3]; py[3] = t0;
        t0 = py[1]; py[1] = py[2]; py[2] = t0;
    }
    if (sa_t < 0.0f) {
        float t0;
        t0 = tx[0]; tx[0] = tx[3]; tx[3] = t0;
        t0 = tx[1]; tx[1] = tx[2]; tx[2] = t0;
        t0 = ty[0]; ty[0] = ty[3]; ty[3] = t0;
        t0 = ty[1]; ty[1] = ty[2]; ty[2] = t0;
    }
    float area_p = fabsf(sa_p);
    float area_t = fabsf(sa_t);

    float bx[8] = {px[0], px[1], px[2], px[3], 0.0f, 0.0f, 0.0f, 0.0f};
    float by[8] = {py[0], py[1], py[2], py[3], 0.0f, 0.0f, 0.0f, 0.0f};
    int n = 4;
#pragma unroll
    for (int k = 0; k < 4; ++k) {
        float Ax = tx[k], Ay = ty[k];
        float Bx = tx[(k + 1) & 3], By = ty[(k + 1) & 3];
        n = clip_halfplane(bx, by, n, Ax, Ay, Bx - Ax, By - Ay);
    }

    // masked shoelace of the clipped polygon
    float acc = 0.0f;
#pragma unroll
    for (int i = 0; i < 8; ++i) {
        bool valid = i < n;
        int ip1 = (i < 7) ? (i + 1) : 7;
        bool wrap = (i + 1 == n);
        float nx = wrap ? bx[0] : bx[ip1];
        float ny = wrap ? by[0] : by[ip1];
        float term = bx[i] * ny - by[i] * nx;
        acc += valid ? term : 0.0f;
    }
    float inter = fabsf(0.5f * acc);
    float uni = area_p + area_t - inter;
    float iou = inter / (uni + FEPS);

    float cpx = 0.25f * (px[0] + px[1] + px[2] + px[3]);
    float cpy = 0.25f * (py[0] + py[1] + py[2] + py[3]);
    float ctx = 0.25f * (tx[0] + tx[1] + tx[2] + tx[3]);
    float cty = 0.25f * (ty[0] + ty[1] + ty[2] + ty[3]);
    float d2 = (cpx - ctx) * (cpx - ctx) + (cpy - cty) * (cpy - cty);

    float minx = fminf(fminf(fminf(px[0], px[1]), fminf(px[2], px[3])),
                       fminf(fminf(tx[0], tx[1]), fminf(tx[2], tx[3])));
    float maxx = fmaxf(fmaxf(fmaxf(px[0], px[1]), fmaxf(px[2], px[3])),
                       fmaxf(fmaxf(tx[0], tx[1]), fmaxf(tx[2], tx[3])));
    float miny = fminf(fminf(fminf(py[0], py[1]), fminf(py[2], py[3])),
                       fminf(fminf(ty[0], ty[1]), fminf(ty[2], ty[3])));
    float maxy = fmaxf(fmaxf(fmaxf(py[0], py[1]), fmaxf(py[2], py[3])),
                       fmaxf(fmaxf(ty[0], ty[1]), fmaxf(ty[2], ty[3])));
    float c2 = (maxx - minx) * (maxx - minx) + (maxy - miny) * (maxy - miny) + FEPS;

    return 1.0f - iou + d2 / c2;
}

__global__ __launch_bounds__(NTHREADS) void diou_main(const float* __restrict__ pred,
                                                      const float* __restrict__ target,
                                                      double* __restrict__ partial,
                                                      int N) {
    const float4* p4 = reinterpret_cast<const float4*>(pred);
    const float4* t4 = reinterpret_cast<const float4*>(target);

    double acc = 0.0;
    for (int i = blockIdx.x * NTHREADS + threadIdx.x; i < N; i += NBLOCKS * NTHREADS) {
        float4 pa = p4[2 * i], pb = p4[2 * i + 1];
        float4 ta = t4[2 * i], tb = t4[2 * i + 1];
        acc += (double)diou_quad(pa, pb, ta, tb);
    }

    __shared__ double s[NTHREADS];
    s[threadIdx.x] = acc;
    __syncthreads();
#pragma unroll
    for (int off = NTHREADS / 2; off > 0; off >>= 1) {
        if (threadIdx.x < off) s[threadIdx.x] += s[threadIdx.x + off];
        __syncthreads();
    }
    if (threadIdx.x == 0) partial[blockIdx.x] = s[0];
}

__global__ __launch_bounds__(256) void diou_finalize(const double* __restrict__ partial,
                                                     float* __restrict__ out,
                                                     int nparts, double invN) {
    __shared__ double s[256];
    double acc = 0.0;
    for (int i = threadIdx.x; i < nparts; i += 256) acc += partial[i];
    s[threadIdx.x] = acc;
    __syncthreads();
#pragma unroll
    for (int off = 128; off > 0; off >>= 1) {
        if (threadIdx.x < off) s[threadIdx.x] += s[threadIdx.x + off];
        __syncthreads();
    }
    if (threadIdx.x == 0) out[0] = (float)(s[0] * invN);
}

extern "C" void kernel_launch(void* const* d_in, const int* in_sizes, int n_in,
                              void* d_out, int out_size, void* d_ws, size_t ws_size,
                              hipStream_t stream) {
    const float* pred = (const float*)d_in[0];
    const float* target = (const float*)d_in[1];
    float* out = (float*)d_out;
    int N = in_sizes[0] / 8;

    double* partial = (double*)d_ws;  // NBLOCKS doubles = 8 KiB scratch

    diou_main<<<NBLOCKS, NTHREADS, 0, stream>>>(pred, target, partial, N);
    diou_finalize<<<1, 256, 0, stream>>>(partial, out, NBLOCKS, 1.0 / (double)N);
}

// Round 2
// 57.649 us; speedup vs baseline: 2.0074x; 2.0074x over previous
//
#include <hip/hip_runtime.h>

#define NBLOCKS 2048
#define NTHREADS 256
#define FEPS 1e-7f

__device__ __forceinline__ float frcp(float x) { return __builtin_amdgcn_rcpf(x); }

// ---------------------------------------------------------------------------
// Clip 1: input polygon is exactly the 4 pred vertices in registers (n==4),
// so reference iterations 4..7 are no-ops. Appends scatter into LDS
// (slot = min(m,7), or slot 8 = trash when the append predicate is false).
// base[s*NTHREADS] is this thread's slot s.
// ---------------------------------------------------------------------------
__device__ __forceinline__ int clip1_to_lds(float2* base,
                                            const float (&px)[4], const float (&py)[4],
                                            float Ax, float Ay, float ex, float ey) {
    float c[4];
#pragma unroll
    for (int j = 0; j < 4; ++j)
        c[j] = ex * (py[j] - Ay) - ey * (px[j] - Ax);
    int m = 0;
#pragma unroll
    for (int i = 0; i < 4; ++i) {
        int ip1 = (i + 1) & 3;  // mod(i+1, n=4)
        float dc = c[i], dn = c[ip1];
        float nx = px[ip1], ny = py[ip1];
        float denom = dc - dn;
        float d = (fabsf(denom) < FEPS) ? 1.0f : denom;
        float t = dc * frcp(d);
        float ipx = px[i] + t * (nx - px[i]);
        float ipy = py[i] + t * (ny - py[i]);
        bool sc = dc >= 0.0f, sn = dn >= 0.0f;

        bool add_cur = sc;  // valid always true (i < 4 == n)
        int i1 = add_cur ? ((m < 7) ? m : 7) : 8;
        base[i1 * NTHREADS] = make_float2(px[i], py[i]);
        m += add_cur ? 1 : 0;

        bool add_ip = (sc != sn);
        int i2 = add_ip ? ((m < 7) ? m : 7) : 8;
        base[i2 * NTHREADS] = make_float2(ipx, ipy);
        m += add_ip ? 1 : 0;
    }
    return m;
}

// ---------------------------------------------------------------------------
// Clips 2..4: read all 8 slots to registers up front (static indices), then
// scatter appends back into the same LDS slots. Reference semantics kept:
// valid = i<n, wrap = (i+1==n), OOB gather clamps to slot 7, idx = min(m,7).
// Slots >= m hold stale garbage — never consumed (masked by valid/wrap).
// ---------------------------------------------------------------------------
__device__ __forceinline__ int clip_lds(float2* base, int n,
                                        float Ax, float Ay, float ex, float ey) {
    float vx[8], vy[8], c[8];
#pragma unroll
    for (int j = 0; j < 8; ++j) {
        float2 v = base[j * NTHREADS];
        vx[j] = v.x; vy[j] = v.y;
    }
#pragma unroll
    for (int j = 0; j < 8; ++j)
        c[j] = ex * (vy[j] - Ay) - ey * (vx[j] - Ax);
    int m = 0;
#pragma unroll
    for (int i = 0; i < 8; ++i) {
        bool valid = i < n;
        bool wrap = (i + 1 == n);
        int ip1 = (i < 7) ? (i + 1) : 7;  // JAX OOB gather clamp
        float nx = wrap ? vx[0] : vx[ip1];
        float ny = wrap ? vy[0] : vy[ip1];
        float dc = c[i];
        float dn = wrap ? c[0] : c[ip1];
        float denom = dc - dn;
        float d = (fabsf(denom) < FEPS) ? 1.0f : denom;
        float t = dc * frcp(d);
        float ipx = vx[i] + t * (nx - vx[i]);
        float ipy = vy[i] + t * (ny - vy[i]);
        bool sc = dc >= 0.0f, sn = dn >= 0.0f;

        bool add_cur = valid && sc;
        int i1 = add_cur ? ((m < 7) ? m : 7) : 8;
        base[i1 * NTHREADS] = make_float2(vx[i], vy[i]);
        m += add_cur ? 1 : 0;

        bool add_ip = valid && (sc != sn);
        int i2 = add_ip ? ((m < 7) ? m : 7) : 8;
        base[i2 * NTHREADS] = make_float2(ipx, ipy);
        m += add_ip ? 1 : 0;
    }
    return m;
}

__device__ __forceinline__ float diou_quad(float2* base,
                                           float4 pa, float4 pb, float4 ta, float4 tb) {
    float px[4] = {pa.x, pa.z, pb.x, pb.z};
    float py[4] = {pa.y, pa.w, pb.y, pb.w};
    float tx[4] = {ta.x, ta.z, tb.x, tb.z};
    float ty[4] = {ta.y, ta.w, tb.y, tb.w};

    float sa_p = 0.5f * ((px[0] * py[1] - py[0] * px[1]) +
                         (px[1] * py[2] - py[1] * px[2]) +
                         (px[2] * py[3] - py[2] * px[3]) +
                         (px[3] * py[0] - py[3] * px[0]));
    float sa_t = 0.5f * ((tx[0] * ty[1] - ty[0] * tx[1]) +
                         (tx[1] * ty[2] - ty[1] * tx[2]) +
                         (tx[2] * ty[3] - ty[2] * tx[3]) +
                         (tx[3] * ty[0] - ty[3] * tx[0]));

    if (sa_p < 0.0f) {  // reverse -> CCW
        float t0;
        t0 = px[0]; px[0] = px[3]; px[3] = t0;
        t0 = px[1]; px[1] = px[2]; px[2] = t0;
        t0 = py[0]; py[0] = py[3]; py[3] = t0;
        t0 = py[1]; py[1] = py[2]; py[2] = t0;
    }
    if (sa_t < 0.0f) {
        float t0;
        t0 = tx[0]; tx[0] = tx[3]; tx[3] = t0;
        t0 = tx[1]; tx[1] = tx[2]; tx[2] = t0;
        t0 = ty[0]; ty[0] = ty[3]; ty[3] = t0;
        t0 = ty[1]; ty[1] = ty[2]; ty[2] = t0;
    }
    float area_p = fabsf(sa_p);
    float area_t = fabsf(sa_t);

    int n = clip1_to_lds(base, px, py, tx[0], ty[0], tx[1] - tx[0], ty[1] - ty[0]);
    n = clip_lds(base, n, tx[1], ty[1], tx[2] - tx[1], ty[2] - ty[1]);
    n = clip_lds(base, n, tx[2], ty[2], tx[3] - tx[2], ty[3] - ty[2]);
    n = clip_lds(base, n, tx[3], ty[3], tx[0] - tx[3], ty[0] - ty[3]);

    // masked shoelace of the clipped polygon (read back to registers)
    float vx[8], vy[8];
#pragma unroll
    for (int j = 0; j < 8; ++j) {
        float2 v = base[j * NTHREADS];
        vx[j] = v.x; vy[j] = v.y;
    }
    float acc = 0.0f;
#pragma unroll
    for (int i = 0; i < 8; ++i) {
        bool valid = i < n;
        bool wrap = (i + 1 == n);
        int ip1 = (i < 7) ? (i + 1) : 7;
        float nx = wrap ? vx[0] : vx[ip1];
        float ny = wrap ? vy[0] : vy[ip1];
        float term = vx[i] * ny - vy[i] * nx;
        acc += valid ? term : 0.0f;
    }
    float inter = fabsf(0.5f * acc);
    float uni = area_p + area_t - inter;
    float iou = inter * frcp(uni + FEPS);

    float cpx = 0.25f * (px[0] + px[1] + px[2] + px[3]);
    float cpy = 0.25f * (py[0] + py[1] + py[2] + py[3]);
    float ctx = 0.25f * (tx[0] + tx[1] + tx[2] + tx[3]);
    float cty = 0.25f * (ty[0] + ty[1] + ty[2] + ty[3]);
    float d2 = (cpx - ctx) * (cpx - ctx) + (cpy - cty) * (cpy - cty);

    float minx = fminf(fminf(fminf(px[0], px[1]), fminf(px[2], px[3])),
                       fminf(fminf(tx[0], tx[1]), fminf(tx[2], tx[3])));
    float maxx = fmaxf(fmaxf(fmaxf(px[0], px[1]), fmaxf(px[2], px[3])),
                       fmaxf(fmaxf(tx[0], tx[1]), fmaxf(tx[2], tx[3])));
    float miny = fminf(fminf(fminf(py[0], py[1]), fminf(py[2], py[3])),
                       fminf(fminf(ty[0], ty[1]), fminf(ty[2], ty[3])));
    float maxy = fmaxf(fmaxf(fmaxf(py[0], py[1]), fmaxf(py[2], py[3])),
                       fmaxf(fmaxf(ty[0], ty[1]), fmaxf(ty[2], ty[3])));
    float c2 = (maxx - minx) * (maxx - minx) + (maxy - miny) * (maxy - miny) + FEPS;

    return 1.0f - iou + d2 * frcp(c2);
}

__global__ __launch_bounds__(NTHREADS) void diou_main(const float* __restrict__ pred,
                                                      const float* __restrict__ target,
                                                      double* __restrict__ partial,
                                                      int N) {
    // 9 slots/thread: 8 polygon + 1 trash (predicated-off scatter target)
    __shared__ float2 poly[9 * NTHREADS];
    __shared__ double wsum[NTHREADS / 64];
    float2* base = &poly[threadIdx.x];

    const float4* p4 = reinterpret_cast<const float4*>(pred);
    const float4* t4 = reinterpret_cast<const float4*>(target);

    double acc = 0.0;
    for (int i = blockIdx.x * NTHREADS + threadIdx.x; i < N; i += NBLOCKS * NTHREADS) {
        float4 pa = p4[2 * i], pb = p4[2 * i + 1];
        float4 ta = t4[2 * i], tb = t4[2 * i + 1];
        acc += (double)diou_quad(base, pa, pb, ta, tb);
    }

    // wave shuffle reduction, then cross-wave via tiny LDS
#pragma unroll
    for (int off = 32; off > 0; off >>= 1) acc += __shfl_down(acc, off, 64);
    int lane = threadIdx.x & 63, wid = threadIdx.x >> 6;
    if (lane == 0) wsum[wid] = acc;
    __syncthreads();
    if (threadIdx.x == 0) {
        double s = 0.0;
#pragma unroll
        for (int w = 0; w < NTHREADS / 64; ++w) s += wsum[w];
        partial[blockIdx.x] = s;
    }
}

__global__ __launch_bounds__(256) void diou_finalize(const double* __restrict__ partial,
                                                     float* __restrict__ out,
                                                     int nparts, double invN) {
    __shared__ double s[256];
    double acc = 0.0;
    for (int i = threadIdx.x; i < nparts; i += 256) acc += partial[i];
    s[threadIdx.x] = acc;
    __syncthreads();
#pragma unroll
    for (int off = 128; off > 0; off >>= 1) {
        if (threadIdx.x < off) s[threadIdx.x] += s[threadIdx.x + off];
        __syncthreads();
    }
    if (threadIdx.x == 0) out[0] = (float)(s[0] * invN);
}

extern "C" void kernel_launch(void* const* d_in, const int* in_sizes, int n_in,
                              void* d_out, int out_size, void* d_ws, size_t ws_size,
                              hipStream_t stream) {
    const float* pred = (const float*)d_in[0];
    const float* target = (const float*)d_in[1];
    float* out = (float*)d_out;
    int N = in_sizes[0] / 8;

    double* partial = (double*)d_ws;  // NBLOCKS doubles = 16 KiB scratch

    diou_main<<<NBLOCKS, NTHREADS, 0, stream>>>(pred, target, partial, N);
    diou_finalize<<<1, 256, 0, stream>>>(partial, out, NBLOCKS, 1.0 / (double)N);
}

// Round 3
// 50.422 us; speedup vs baseline: 2.2952x; 1.1433x over previous
//
#include <hip/hip_runtime.h>

#define NBLOCKS 2048
#define NTHREADS 256
#define FEPS 1e-7f

__device__ __forceinline__ float frcp(float x) { return __builtin_amdgcn_rcpf(x); }

// ---------------------------------------------------------------------------
// Clip 1: input polygon is exactly the 4 pred vertices (n==4) in registers;
// reference iterations 4..7 are provably no-ops. Appends scatter into LDS
// (slot = m, no clamp needed since m<=7 always; slot 8 = trash when the
// append predicate is false). base[s*NTHREADS] is this thread's slot s.
// c[j] = ex*vy[j] - ey*vx[j] - h with h = ex*Ay - ey*Ax (same sign semantics
// as the reference cross, re-associated).
// ---------------------------------------------------------------------------
__device__ __forceinline__ int clip1_to_lds(float2* base,
                                            const float (&px)[4], const float (&py)[4],
                                            float ex, float ey, float h) {
    float c[4];
#pragma unroll
    for (int j = 0; j < 4; ++j)
        c[j] = fmaf(ex, py[j], -fmaf(ey, px[j], h));
    int m = 0;
#pragma unroll
    for (int i = 0; i < 4; ++i) {
        const int ip1 = (i + 1) & 3;  // mod(i+1, n=4)
        float dc = c[i], dn = c[ip1];
        float nx = px[ip1], ny = py[ip1];
        float denom = dc - dn;
        float d = (fabsf(denom) < FEPS) ? 1.0f : denom;
        float t = dc * frcp(d);
        float ipx = fmaf(t, nx - px[i], px[i]);
        float ipy = fmaf(t, ny - py[i], py[i]);
        bool sc = dc >= 0.0f, sn = dn >= 0.0f;

        bool add_cur = sc;
        int i1 = add_cur ? m : 8;          // m <= 2i <= 6: no clamp
        base[i1 * NTHREADS] = make_float2(px[i], py[i]);
        m += add_cur;

        bool add_ip = (sc != sn);
        int i2 = add_ip ? m : 8;           // m <= 7: no clamp
        base[i2 * NTHREADS] = make_float2(ipx, ipy);
        m += add_ip;
    }
    return m;
}

// ---------------------------------------------------------------------------
// Clips 2..4: read all 8 slots to registers up front (static indices), then
// scatter appends back into the same LDS slots. Reference semantics kept:
// valid = i<n, wrap = (i+1==n), OOB gather clamps to slot 7, idx = min(m,7)
// (elided where m<=2i proves it a no-op). Iterations where NO lane is valid
// are exact no-ops (trash writes only, m unchanged) -> wave-uniform break.
// ---------------------------------------------------------------------------
__device__ __forceinline__ int clip_lds(float2* base, int n,
                                        float ex, float ey, float h) {
    float vx[8], vy[8], c[8];
#pragma unroll
    for (int j = 0; j < 8; ++j) {
        float2 v = base[j * NTHREADS];
        vx[j] = v.x; vy[j] = v.y;
        c[j] = fmaf(ex, vy[j], -fmaf(ey, vx[j], h));
    }
    int m = 0;
#pragma unroll
    for (int i = 0; i < 8; ++i) {
        if (i >= 4 && !__any(i < n)) break;
        bool valid = i < n;
        bool wrap = (i + 1 == n);
        const int ip1 = (i < 7) ? (i + 1) : 7;  // JAX OOB gather clamp
        float nx = wrap ? vx[0] : vx[ip1];
        float ny = wrap ? vy[0] : vy[ip1];
        float dc = c[i];
        float dn = wrap ? c[0] : c[ip1];
        float denom = dc - dn;
        float d = (fabsf(denom) < FEPS) ? 1.0f : denom;
        float t = dc * frcp(d);
        float ipx = fmaf(t, nx - vx[i], vx[i]);
        float ipy = fmaf(t, ny - vy[i], vy[i]);
        bool sc = dc >= 0.0f, sn = dn >= 0.0f;

        bool add_cur = valid && sc;
        int i1;
        if (i < 4) i1 = add_cur ? m : 8;                    // m <= 2i <= 6
        else       i1 = add_cur ? ((m < 7) ? m : 7) : 8;
        base[i1 * NTHREADS] = make_float2(vx[i], vy[i]);
        m += add_cur;

        bool add_ip = valid && (sc != sn);
        int i2;
        if (i < 4) i2 = add_ip ? m : 8;                     // m <= 2i+1 <= 7
        else       i2 = add_ip ? ((m < 7) ? m : 7) : 8;
        base[i2 * NTHREADS] = make_float2(ipx, ipy);
        m += add_ip;
    }
    return m;
}

__device__ __forceinline__ float diou_quad(float2* base,
                                           float4 pa, float4 pb, float4 ta, float4 tb) {
    float px[4] = {pa.x, pa.z, pb.x, pb.z};
    float py[4] = {pa.y, pa.w, pb.y, pb.w};
    float tx[4] = {ta.x, ta.z, tb.x, tb.z};
    float ty[4] = {ta.y, ta.w, tb.y, tb.w};

    float sa_p = 0.5f * ((px[0] * py[1] - py[0] * px[1]) +
                         (px[1] * py[2] - py[1] * px[2]) +
                         (px[2] * py[3] - py[2] * px[3]) +
                         (px[3] * py[0] - py[3] * px[0]));
    float sa_t = 0.5f * ((tx[0] * ty[1] - ty[0] * tx[1]) +
                         (tx[1] * ty[2] - ty[1] * tx[2]) +
                         (tx[2] * ty[3] - ty[2] * tx[3]) +
                         (tx[3] * ty[0] - ty[3] * tx[0]));

    if (sa_p < 0.0f) {  // reverse -> CCW (centers/minmax invariant to order)
        float t0;
        t0 = px[0]; px[0] = px[3]; px[3] = t0;
        t0 = px[1]; px[1] = px[2]; px[2] = t0;
        t0 = py[0]; py[0] = py[3]; py[3] = t0;
        t0 = py[1]; py[1] = py[2]; py[2] = t0;
    }
    if (sa_t < 0.0f) {
        float t0;
        t0 = tx[0]; tx[0] = tx[3]; tx[3] = t0;
        t0 = tx[1]; tx[1] = tx[2]; tx[2] = t0;
        t0 = ty[0]; ty[0] = ty[3]; ty[3] = t0;
        t0 = ty[1]; ty[1] = ty[2]; ty[2] = t0;
    }
    float area_p = fabsf(sa_p);
    float area_t = fabsf(sa_t);

    int n;
    {
        float ex = tx[1] - tx[0], ey = ty[1] - ty[0];
        n = clip1_to_lds(base, px, py, ex, ey, fmaf(ex, ty[0], -ey * tx[0]));
    }
    {
        float ex = tx[2] - tx[1], ey = ty[2] - ty[1];
        n = clip_lds(base, n, ex, ey, fmaf(ex, ty[1], -ey * tx[1]));
    }
    {
        float ex = tx[3] - tx[2], ey = ty[3] - ty[2];
        n = clip_lds(base, n, ex, ey, fmaf(ex, ty[2], -ey * tx[2]));
    }
    {
        float ex = tx[0] - tx[3], ey = ty[0] - ty[3];
        n = clip_lds(base, n, ex, ey, fmaf(ex, ty[3], -ey * tx[3]));
    }

    // masked shoelace of the clipped polygon (read back to registers)
    float vx[8], vy[8];
#pragma unroll
    for (int j = 0; j < 8; ++j) {
        float2 v = base[j * NTHREADS];
        vx[j] = v.x; vy[j] = v.y;
    }
    float acc = 0.0f;
#pragma unroll
    for (int i = 0; i < 8; ++i) {
        if (i >= 4 && !__any(i < n)) break;
        bool valid = i < n;
        bool wrap = (i + 1 == n);
        const int ip1 = (i < 7) ? (i + 1) : 7;
        float nx = wrap ? vx[0] : vx[ip1];
        float ny = wrap ? vy[0] : vy[ip1];
        float term = vx[i] * ny - vy[i] * nx;
        acc += valid ? term : 0.0f;
    }
    float inter = fabsf(0.5f * acc);
    float uni = area_p + area_t - inter;
    float iou = inter * frcp(uni + FEPS);

    float cpx = 0.25f * (px[0] + px[1] + px[2] + px[3]);
    float cpy = 0.25f * (py[0] + py[1] + py[2] + py[3]);
    float ctx = 0.25f * (tx[0] + tx[1] + tx[2] + tx[3]);
    float cty = 0.25f * (ty[0] + ty[1] + ty[2] + ty[3]);
    float d2 = (cpx - ctx) * (cpx - ctx) + (cpy - cty) * (cpy - cty);

    float minx = fminf(fminf(fminf(px[0], px[1]), fminf(px[2], px[3])),
                       fminf(fminf(tx[0], tx[1]), fminf(tx[2], tx[3])));
    float maxx = fmaxf(fmaxf(fmaxf(px[0], px[1]), fmaxf(px[2], px[3])),
                       fmaxf(fmaxf(tx[0], tx[1]), fmaxf(tx[2], tx[3])));
    float miny = fminf(fminf(fminf(py[0], py[1]), fminf(py[2], py[3])),
                       fminf(fminf(ty[0], ty[1]), fminf(ty[2], ty[3])));
    float maxy = fmaxf(fmaxf(fmaxf(py[0], py[1]), fmaxf(py[2], py[3])),
                       fmaxf(fmaxf(ty[0], ty[1]), fmaxf(ty[2], ty[3])));
    float c2 = (maxx - minx) * (maxx - minx) + (maxy - miny) * (maxy - miny) + FEPS;

    return 1.0f - iou + d2 * frcp(c2);
}

__global__ __launch_bounds__(NTHREADS, 6) void diou_main(const float* __restrict__ pred,
                                                         const float* __restrict__ target,
                                                         double* __restrict__ partial,
                                                         int N) {
    // 9 slots/thread: 8 polygon + 1 trash (predicated-off scatter target).
    // Slot stride = NTHREADS*8B = 2048B -> bank = 2*lane mod 32 regardless of
    // slot: every access is 2-way (free) -> SQ_LDS_BANK_CONFLICT stays 0.
    __shared__ float2 poly[9 * NTHREADS];
    __shared__ double wsum[NTHREADS / 64];
    float2* base = &poly[threadIdx.x];

    const float4* p4 = reinterpret_cast<const float4*>(pred);
    const float4* t4 = reinterpret_cast<const float4*>(target);

    double acc = 0.0;
    for (int i = blockIdx.x * NTHREADS + threadIdx.x; i < N; i += NBLOCKS * NTHREADS) {
        float4 pa = p4[2 * i], pb = p4[2 * i + 1];
        float4 ta = t4[2 * i], tb = t4[2 * i + 1];
        acc += (double)diou_quad(base, pa, pb, ta, tb);
    }

    // wave shuffle reduction, then cross-wave via tiny LDS
#pragma unroll
    for (int off = 32; off > 0; off >>= 1) acc += __shfl_down(acc, off, 64);
    int lane = threadIdx.x & 63, wid = threadIdx.x >> 6;
    if (lane == 0) wsum[wid] = acc;
    __syncthreads();
    if (threadIdx.x == 0) {
        double s = 0.0;
#pragma unroll
        for (int w = 0; w < NTHREADS / 64; ++w) s += wsum[w];
        partial[blockIdx.x] = s;
    }
}

__global__ __launch_bounds__(256) void diou_finalize(const double* __restrict__ partial,
                                                     float* __restrict__ out,
                                                     int nparts, double invN) {
    __shared__ double s[256];
    double acc = 0.0;
    for (int i = threadIdx.x; i < nparts; i += 256) acc += partial[i];
    s[threadIdx.x] = acc;
    __syncthreads();
#pragma unroll
    for (int off = 128; off > 0; off >>= 1) {
        if (threadIdx.x < off) s[threadIdx.x] += s[threadIdx.x + off];
        __syncthreads();
    }
    if (threadIdx.x == 0) out[0] = (float)(s[0] * invN);
}

extern "C" void kernel_launch(void* const* d_in, const int* in_sizes, int n_in,
                              void* d_out, int out_size, void* d_ws, size_t ws_size,
                              hipStream_t stream) {
    const float* pred = (const float*)d_in[0];
    const float* target = (const float*)d_in[1];
    float* out = (float*)d_out;
    int N = in_sizes[0] / 8;

    double* partial = (double*)d_ws;  // NBLOCKS doubles = 16 KiB scratch

    diou_main<<<NBLOCKS, NTHREADS, 0, stream>>>(pred, target, partial, N);
    diou_finalize<<<1, 256, 0, stream>>>(partial, out, NBLOCKS, 1.0 / (double)N);
}